// Round 13
// baseline (99.345 us; speedup 1.0000x reference)
//
#include <hip/hip_runtime.h>

#define RADIUS 3
#define C_CH 128
#define NG 16               // channel groups of 8
#define N_FR 16
#define H0 120
#define W0 160
#define HW0 (H0*W0)
#define H1 30
#define W1 40
#define HW1 (H1*W1)
#define EXT 10
#define NCELL 100
#define M_PT 1536
#define SCSTR 12
#define NBKT 256

typedef _Float16 half2v __attribute__((ext_vector_type(2)));
typedef _Float16 f16x8 __attribute__((ext_vector_type(8)));
typedef float f32x4 __attribute__((ext_vector_type(4)));
union Q { uint4 u4; half2v h[4]; };
union AB { uint4 u4; f16x8 h8; };

__device__ __forceinline__ unsigned pack2h(float a, float b) {
    union { _Float16 h[2]; unsigned u; } x;
    x.h[0] = (_Float16)a; x.h[1] = (_Float16)b;
    return x.u;
}

// ---- fat prep: blocks [0, nPack) = pack+pool strips; [nPack, nPack+M) = gpack ----
__global__ __launch_bounds__(256) void prep_fat(const float* __restrict__ fm0,
                                                uint4* __restrict__ fH,
                                                uint4* __restrict__ f1H,
                                                const float* __restrict__ g,
                                                unsigned* __restrict__ gH) {
    __shared__ char shraw[4 * W0 * 16];          // 10240 B (>= 4608 for gpack)
    const int nPack = N_FR * NG * H1;
    int tid = threadIdx.x;

    if (blockIdx.x < nPack) {
        uint4 (*s)[W0] = reinterpret_cast<uint4 (*)[W0]>(shraw);
        int blk = blockIdx.x;               // (n*NG + g)*H1 + yo
        int yo = blk % H1;
        int ng = blk / H1;
        int gg = ng & (NG - 1);
        int n = ng / NG;
        int y0 = yo * 4;
        const float* src0 = fm0 + ((size_t)(n * C_CH + gg * 8)) * HW0;
        uint4* dst = fH + ((size_t)ng * H0 + y0) * W0;

        for (int t = tid; t < 4 * W0; t += 256) {
            int yl = t / W0, x = t - yl * W0;
            const float* src = src0 + (size_t)(y0 + yl) * W0 + x;
            uint4 o;
            o.x = pack2h(src[0],             src[(size_t)HW0]);
            o.y = pack2h(src[2*(size_t)HW0], src[3*(size_t)HW0]);
            o.z = pack2h(src[4*(size_t)HW0], src[5*(size_t)HW0]);
            o.w = pack2h(src[6*(size_t)HW0], src[7*(size_t)HW0]);
            s[yl][x] = o;
            dst[t] = o;
        }
        __syncthreads();

        if (tid < W1) {
            int xo = tid;
            float sm[8];
#pragma unroll
            for (int k = 0; k < 8; ++k) sm[k] = 0.f;
#pragma unroll
            for (int yl = 0; yl < 4; ++yl) {
#pragma unroll
                for (int dx = 0; dx < 4; ++dx) {
                    Q qv; qv.u4 = s[yl][xo * 4 + dx];
#pragma unroll
                    for (int k = 0; k < 4; ++k) {
                        sm[2*k]   += (float)qv.h[k].x;
                        sm[2*k+1] += (float)qv.h[k].y;
                    }
                }
            }
            uint4 o;
            o.x = pack2h(sm[0] * (1.f/16.f), sm[1] * (1.f/16.f));
            o.y = pack2h(sm[2] * (1.f/16.f), sm[3] * (1.f/16.f));
            o.z = pack2h(sm[4] * (1.f/16.f), sm[5] * (1.f/16.f));
            o.w = pack2h(sm[6] * (1.f/16.f), sm[7] * (1.f/16.f));
            f1H[(size_t)ng * HW1 + yo * W1 + xo] = o;
        }
    } else {
        float* s = reinterpret_cast<float*>(shraw);
        int m = blockIdx.x - nPack;
        const float* src = g + (size_t)m * (C_CH * 9);
        for (int t = tid; t < C_CH * 9; t += 256) s[t] = src[t];
        __syncthreads();
        unsigned* dst = gH + (size_t)m * (9 * 64);
        for (int t = tid; t < 9 * 64; t += 256) {
            int pq = t >> 6, pr = t & 63;
            dst[t] = pack2h(s[(2 * pr) * 9 + pq], s[(2 * pr + 1) * 9 + pq]);
        }
    }
}

// ---- (frame, y-band) single-block sort: hist + scan + scatter in one kernel ----
__device__ __forceinline__ int sort_key(const int* jj, const float* coords, int e) {
    float cy = coords[(size_t)e * 18 + 1];
    int by0 = (int)floorf(cy) - RADIUS;
    int band = min(max(by0 >> 3, 0), 15);
    return jj[e] * 16 + band;
}

__global__ __launch_bounds__(1024) void sort_all(const int* __restrict__ jj,
                                                 const float* __restrict__ coords,
                                                 int* __restrict__ perm, int E) {
    __shared__ int h[NBKT];
    __shared__ int off[NBKT];
    int tid = threadIdx.x;
    if (tid < NBKT) h[tid] = 0;
    __syncthreads();
    for (int e = tid; e < E; e += 1024) atomicAdd(&h[sort_key(jj, coords, e)], 1);
    __syncthreads();
    if (tid == 0) {
        int s = 0;
        for (int f = 0; f < NBKT; ++f) { off[f] = s; s += h[f]; }
    }
    __syncthreads();
    for (int e = tid; e < E; e += 1024) {
        int k = sort_key(jj, coords, e);
        int r = atomicAdd(&off[k], 1);
        perm[r] = e;
    }
}

// ---- MFMA corr: one wave per edge; B-frags hoisted; float2 epilogue ----
__global__ __launch_bounds__(64, 4) void corr_mfma(
        const uint4* __restrict__ fH,    // [N,16,H0,W0] uint4
        const uint4* __restrict__ f1H,   // [N,16,H1,W1] uint4
        const uint4* __restrict__ gH4,   // [M,9,16] uint4
        const float* __restrict__ coords,
        const int* __restrict__ ii,
        const int* __restrict__ jj,
        const int* __restrict__ perm,
        float* __restrict__ out) {
    __shared__ float sC[2 * NCELL * SCSTR];

    int nwg = gridDim.x;
    int q = nwg >> 3, r = nwg & 7;
    int xcd = blockIdx.x & 7;
    int ib = blockIdx.x >> 3;
    int orig = (xcd < r ? xcd * (q + 1) : r * (q + 1) + (xcd - r) * q) + ib;
    int e = perm ? perm[orig] : orig;

    int l = threadIdx.x;
    int lrow = l & 15;        // A row (cell-in-tile) / B col (pq)
    int lk = l >> 4;          // k-chunk 0..3 (8 channels each)

    int iie = __builtin_amdgcn_readfirstlane(ii[e]);
    int jje = __builtin_amdgcn_readfirstlane(jj[e]);
    const float* cb = coords + (size_t)e * 18;

    float cx = cb[0], cy = cb[1];
    int bx0 = (int)floorf(cx) - RADIUS;
    int by0 = (int)floorf(cy) - RADIUS;
    int bx1 = (int)floorf(cx * 0.25f) - RADIUS;
    int by1 = (int)floorf(cy * 0.25f) - RADIUS;

    // hoist all 4 B-fragments (16 VGPR)
    int pqc = min(lrow, 8);
    const uint4* gb = gH4 + (size_t)iie * 144 + pqc * 16 + lk;
    AB bfr[4];
#pragma unroll
    for (int kk = 0; kk < 4; ++kk) bfr[kk].u4 = gb[kk * 4];

    int off0[7], off1[7];
#pragma unroll
    for (int t = 0; t < 7; ++t) {
        int c = min(t * 16 + lrow, NCELL - 1);
        int iy = c / EXT, ix = c - iy * EXT;
        int gy0 = min(max(by0 + iy, 0), H0 - 1);
        int gx0 = min(max(bx0 + ix, 0), W0 - 1);
        int gy1 = min(max(by1 + iy, 0), H1 - 1);
        int gx1 = min(max(bx1 + ix, 0), W1 - 1);
        off0[t] = gy0 * W0 + gx0;
        off1[t] = gy1 * W1 + gx1;
    }

    const uint4* f0 = fH + (size_t)jje * NG * HW0;
    const uint4* f1 = f1H + (size_t)jje * NG * HW1;

    f32x4 acc0[7], acc1[7];
#pragma unroll
    for (int t = 0; t < 7; ++t) {
        acc0[t] = (f32x4){0.f, 0.f, 0.f, 0.f};
        acc1[t] = (f32x4){0.f, 0.f, 0.f, 0.f};
    }

#pragma unroll
    for (int kk = 0; kk < 4; ++kk) {
        const uint4* p0 = f0 + (size_t)(kk * 4 + lk) * HW0;
        const uint4* p1 = f1 + (size_t)(kk * 4 + lk) * HW1;
        AB a[7];
#pragma unroll
        for (int t = 0; t < 7; ++t) a[t].u4 = p0[off0[t]];
#pragma unroll
        for (int t = 0; t < 7; ++t)
            acc0[t] = __builtin_amdgcn_mfma_f32_16x16x32_f16(a[t].h8, bfr[kk].h8, acc0[t], 0, 0, 0);
#pragma unroll
        for (int t = 0; t < 7; ++t) a[t].u4 = p1[off1[t]];
#pragma unroll
        for (int t = 0; t < 7; ++t)
            acc1[t] = __builtin_amdgcn_mfma_f32_16x16x32_f16(a[t].h8, bfr[kk].h8, acc1[t], 0, 0, 0);
    }

    // C layout: col = l&15 (pq), row = (l>>4)*4 + reg (cell-in-tile)
    if (lrow < 9) {
#pragma unroll
        for (int t = 0; t < 7; ++t) {
#pragma unroll
            for (int r2 = 0; r2 < 4; ++r2) {
                int cell = t * 16 + lk * 4 + r2;
                if (cell < NCELL) {
                    sC[cell * SCSTR + lrow] = acc0[t][r2];
                    sC[NCELL * SCSTR + cell * SCSTR + lrow] = acc1[t][r2];
                }
            }
        }
    }
    __syncthreads();

    // float2 epilogue: rr = (a*7+b)*9 + pq, both levels at once, coalesced 8B stores
    float2* op = reinterpret_cast<float2*>(out + (size_t)e * 882);
#pragma unroll
    for (int w = 0; w < 7; ++w) {
        int rr = l + w * 64;
        if (rr < 441) {
            int pq = rr % 9;
            int ab = rr / 9;
            int a = ab / 7, b = ab - a * 7;
            float x0c = cb[pq * 2 + 0];
            float y0c = cb[pq * 2 + 1];
            float2 res;
#pragma unroll
            for (int lvl = 0; lvl < 2; ++lvl) {
                float s = lvl ? 0.25f : 1.f;
                float x = x0c * s;
                float y = y0c * s;
                float x0f = floorf(x), y0f = floorf(y);
                float fx = x - x0f, fy = y - y0f;
                int offx = (int)x0f - RADIUS - (lvl ? bx1 : bx0);
                int offy = (int)y0f - RADIUS - (lvl ? by1 : by0);
                int cell2 = (offy + a) * EXT + (offx + b);
                int base = lvl * (NCELL * SCSTR) + cell2 * SCSTR + pq;
                float c00 = sC[base];
                float c01 = sC[base + SCSTR];
                float c10 = sC[base + EXT * SCSTR];
                float c11 = sC[base + EXT * SCSTR + SCSTR];
                float v = (1.f - fy) * (1.f - fx) * c00 + (1.f - fy) * fx * c01
                        + fy * (1.f - fx) * c10 + fy * fx * c11;
                if (lvl) res.y = v; else res.x = v;
            }
            op[rr] = res;
        }
    }
}

// ---- fp32 fallback (small ws) ----
__global__ __launch_bounds__(256) void pool_fm1T(const float* __restrict__ fm0,
                                                 float* __restrict__ fm1T) {
    __shared__ float s[C_CH * 41];
    int blk = blockIdx.x;
    int yo = blk % H1;
    int n = blk / H1;
    for (int pair = threadIdx.x; pair < C_CH * W1; pair += 256) {
        int c = pair / W1, xo = pair - c * W1;
        const float* p = fm0 + (((size_t)(n * C_CH + c) * H0) + yo * 4) * W0 + xo * 4;
        float sum = 0.f;
#pragma unroll
        for (int yl = 0; yl < 4; ++yl) {
            float4 v = *reinterpret_cast<const float4*>(p + yl * W0);
            sum += v.x + v.y + v.z + v.w;
        }
        s[c * 41 + xo] = sum * (1.f / 16.f);
    }
    __syncthreads();
    float* dp = fm1T + (size_t)blk * W1 * C_CH;
    for (int t = threadIdx.x; t < W1 * C_CH; t += 256) {
        int xo = t >> 7, c = t & 127;
        dp[t] = s[c * 41 + xo];
    }
}

__global__ __launch_bounds__(128) void corr_kernel(
        const float* __restrict__ fmap, const float* __restrict__ fm1T,
        const float* __restrict__ gmap, const float* __restrict__ coords,
        const int* __restrict__ ii, const int* __restrict__ jj,
        float* __restrict__ out) {
    __shared__ float sC[2 * NCELL * SCSTR];
    int e = blockIdx.x;
    int tid = threadIdx.x;
    int iie = __builtin_amdgcn_readfirstlane(ii[e]);
    int jje = __builtin_amdgcn_readfirstlane(jj[e]);
    const float* cb = coords + (size_t)e * 18;
    float cx = cb[0], cy = cb[1];
    int bx0 = (int)floorf(cx) - RADIUS;
    int by0 = (int)floorf(cy) - RADIUS;
    int bx1 = (int)floorf(cx * 0.25f) - RADIUS;
    int by1 = (int)floorf(cy * 0.25f) - RADIUS;
    int cell = min(tid, NCELL - 1);
    int iy = cell / EXT, ix = cell - iy * EXT;
    int gy0 = min(max(by0 + iy, 0), H0 - 1);
    int gx0 = min(max(bx0 + ix, 0), W0 - 1);
    int gy1 = min(max(by1 + iy, 0), H1 - 1);
    int gx1 = min(max(bx1 + ix, 0), W1 - 1);
    const float* fp0 = fmap + (size_t)jje * C_CH * HW0 + gy0 * W0 + gx0;
    const float* fp1 = fm1T + (((size_t)jje * H1 + gy1) * W1 + gx1) * C_CH;
    float acc0[9], acc1[9];
#pragma unroll
    for (int pq = 0; pq < 9; ++pq) { acc0[pq] = 0.f; acc1[pq] = 0.f; }
    const float* gp = gmap + (size_t)iie * (C_CH * 9);
#pragma unroll 2
    for (int c = 0; c < C_CH; c += 4) {
        float f0 = fp0[(size_t)(c + 0) * HW0];
        float f1 = fp0[(size_t)(c + 1) * HW0];
        float f2 = fp0[(size_t)(c + 2) * HW0];
        float f3 = fp0[(size_t)(c + 3) * HW0];
        float4 fv = *reinterpret_cast<const float4*>(fp1 + c);
#pragma unroll
        for (int pq = 0; pq < 9; ++pq) {
            float g0 = gp[(c + 0) * 9 + pq];
            float g1 = gp[(c + 1) * 9 + pq];
            float g2 = gp[(c + 2) * 9 + pq];
            float g3 = gp[(c + 3) * 9 + pq];
            acc0[pq] += f0 * g0 + f1 * g1 + f2 * g2 + f3 * g3;
            acc1[pq] += fv.x * g0 + fv.y * g1 + fv.z * g2 + fv.w * g3;
        }
    }
    if (tid < NCELL) {
        float* s0 = &sC[cell * SCSTR];
        float* s1 = &sC[NCELL * SCSTR + cell * SCSTR];
        *reinterpret_cast<float4*>(s0)     = float4{acc0[0], acc0[1], acc0[2], acc0[3]};
        *reinterpret_cast<float4*>(s0 + 4) = float4{acc0[4], acc0[5], acc0[6], acc0[7]};
        s0[8] = acc0[8];
        *reinterpret_cast<float4*>(s1)     = float4{acc1[0], acc1[1], acc1[2], acc1[3]};
        *reinterpret_cast<float4*>(s1 + 4) = float4{acc1[4], acc1[5], acc1[6], acc1[7]};
        s1[8] = acc1[8];
    }
    __syncthreads();
    for (int o = tid; o < 882; o += 128) {
        int lvl = o & 1;
        int rr = o >> 1;
        int pq = rr % 9;
        int ab = rr / 9;
        int a = ab / 7, b = ab - a * 7;
        float s = lvl ? 0.25f : 1.f;
        float x = cb[pq * 2 + 0] * s;
        float y = cb[pq * 2 + 1] * s;
        float x0f = floorf(x), y0f = floorf(y);
        float fx = x - x0f, fy = y - y0f;
        int offx = (int)x0f - RADIUS - (lvl ? bx1 : bx0);
        int offy = (int)y0f - RADIUS - (lvl ? by1 : by0);
        int cell2 = (offy + a) * EXT + (offx + b);
        int base = lvl * (NCELL * SCSTR) + cell2 * SCSTR + pq;
        float c00 = sC[base];
        float c01 = sC[base + SCSTR];
        float c10 = sC[base + EXT * SCSTR];
        float c11 = sC[base + EXT * SCSTR + SCSTR];
        float v = (1.f - fy) * (1.f - fx) * c00 + (1.f - fy) * fx * c01
                + fy * (1.f - fx) * c10 + fy * fx * c11;
        out[(size_t)e * 882 + (size_t)rr * 2 + lvl] = v;
    }
}

extern "C" void kernel_launch(void* const* d_in, const int* in_sizes, int n_in,
                              void* d_out, int out_size, void* d_ws, size_t ws_size,
                              hipStream_t stream) {
    const float* fmap   = (const float*)d_in[0];
    const float* gmap   = (const float*)d_in[1];
    const float* coords = (const float*)d_in[2];
    const int* ii       = (const int*)d_in[3];
    const int* jj       = (const int*)d_in[4];
    float* out = (float*)d_out;
    int E = in_sizes[3];

    size_t szFH  = (size_t)N_FR * C_CH * HW0 * 2;       // 78.6 MB
    size_t szF1H = (size_t)N_FR * C_CH * HW1 * 2;       // 4.9 MB
    size_t szGH  = (size_t)M_PT * 9 * C_CH * 2 + 4096;  // 3.5 MB (+pad)
    size_t need_h = szFH + szF1H + szGH + (size_t)E * 4;

    if (ws_size >= need_h) {
        uint4* fH  = (uint4*)d_ws;
        uint4* f1H = (uint4*)((char*)d_ws + szFH);
        unsigned* gH = (unsigned*)((char*)d_ws + szFH + szF1H);
        int* perm = (int*)((char*)d_ws + szFH + szF1H + szGH);

        int nPack = N_FR * NG * H1;
        prep_fat<<<nPack + M_PT, 256, 0, stream>>>(fmap, fH, f1H, gmap, gH);
        sort_all<<<1, 1024, 0, stream>>>(jj, coords, perm, E);
        corr_mfma<<<E, 64, 0, stream>>>(fH, f1H, (const uint4*)gH,
                                        coords, ii, jj, perm, out);
        return;
    }

    // ---- fp32 fallback ----
    float* fm1T = (float*)d_ws;
    pool_fm1T<<<N_FR * H1, 256, 0, stream>>>(fmap, fm1T);
    corr_kernel<<<E, 128, 0, stream>>>(fmap, fm1T, gmap, coords, ii, jj, out);
}